// Round 4
// baseline (539.197 us; speedup 1.0000x reference)
//
#include <hip/hip_runtime.h>
#include <hip/hip_bf16.h>

// SS2D fused pipeline for MI355X (gfx950). All fp32.
// K1 in_proj(+silu z) -> K2 dwconv3x3+silu(+transposed copy) -> K3 x_dbl proj
// (emits BC interleaved [l][n]) -> K4a chunk-local carries -> K4b combine
// -> K4c full scan (BC reg-prefetched across barrier, DPP butterfly)
// -> K5a cross-merge (+D*u skip term) -> K5b LayerNorm+gate+out_proj.

#define B_   8
#define H_   48
#define W_   48
#define DM   96
#define DIN  192
#define NST  16
#define RNK  6
#define KD   4
#define L_   (H_*W_)      // 2304
#define NCH  6
#define LC   (L_/NCH)     // 384 = 24 sub-chunks of 16

__device__ __forceinline__ float dpp_xor1(float v) {   // quad_perm [1,0,3,2]
  return __int_as_float(__builtin_amdgcn_update_dpp(
      0, __float_as_int(v), 0xB1, 0xf, 0xf, false));
}
__device__ __forceinline__ float dpp_xor2(float v) {   // quad_perm [2,3,0,1]
  return __int_as_float(__builtin_amdgcn_update_dpp(
      0, __float_as_int(v), 0x4E, 0xf, 0xf, false));
}

// ---------------------------------------------------------------- K1: in_proj
__global__ __launch_bounds__(256) void k1_inproj(
    const float* __restrict__ x, const float* __restrict__ w,
    float* __restrict__ xc_pre, float* __restrict__ z_silu) {
  __shared__ float xs[16][100];
  const int t = threadIdx.x;
  const long row0 = (long)blockIdx.x * 16;
  for (int idx = t; idx < 16*96; idx += 256) {
    int r = idx / 96, c = idx % 96;
    xs[r][c] = x[(row0 + r)*96 + c];
  }
  __syncthreads();
  for (int u = t; u < 2*DIN; u += 256) {
    float acc[16];
    #pragma unroll
    for (int r = 0; r < 16; ++r) acc[r] = 0.f;
    const float4* wrow = (const float4*)(w + u*96);
    #pragma unroll 4
    for (int cq = 0; cq < 24; ++cq) {
      float4 w4 = wrow[cq];
      #pragma unroll
      for (int r = 0; r < 16; ++r) {
        float4 x4 = *((const float4*)&xs[r][cq*4]);
        acc[r] = fmaf(w4.x,x4.x, fmaf(w4.y,x4.y, fmaf(w4.z,x4.z, fmaf(w4.w,x4.w, acc[r]))));
      }
    }
    if (u < DIN) {
      #pragma unroll
      for (int r = 0; r < 16; ++r) xc_pre[(row0 + r)*DIN + u] = acc[r];
    } else {
      #pragma unroll
      for (int r = 0; r < 16; ++r) {
        float v = acc[r];
        z_silu[(row0 + r)*DIN + (u - DIN)] = v / (1.f + __expf(-v));
      }
    }
  }
}

// ------------------------------------------------- K2: depthwise conv + silu
__global__ __launch_bounds__(256) void k2_conv(
    const float* __restrict__ xc_pre, const float* __restrict__ cw,
    const float* __restrict__ cb, float* __restrict__ xc, float* __restrict__ xT) {
  const int bid = blockIdx.x;
  const int tile = bid % 9; const int dc = (bid/9) % 6; const int b = bid / 54;
  const int h0 = (tile/3)*16, w0 = (tile%3)*16, d0 = dc*32;
  __shared__ float tin[32*325];
  __shared__ float tout[8][16][17];
  const int t = threadIdx.x;
  for (int idx = t; idx < 32*18*18; idx += 256) {
    int d2 = idx & 31; int rest = idx >> 5; int ww = rest % 18; int hh = rest / 18;
    int h = h0 + hh - 1, w = w0 + ww - 1;
    float v = 0.f;
    if (h >= 0 && h < H_ && w >= 0 && w < W_)
      v = xc_pre[((long)b*L_ + h*W_ + w)*DIN + d0 + d2];
    tin[d2*325 + hh*18 + ww] = v;
  }
  __syncthreads();
  const int hh = t >> 4, ww = t & 15;
  for (int oct = 0; oct < 4; ++oct) {
    #pragma unroll
    for (int q = 0; q < 8; ++q) {
      const int d2 = oct*8 + q;
      const int d = d0 + d2;
      float acc = cb[d];
      const float* k9 = &cw[d*9];
      const float* base = &tin[d2*325];
      #pragma unroll
      for (int i = 0; i < 3; ++i)
        #pragma unroll
        for (int j = 0; j < 3; ++j)
          acc = fmaf(base[(hh+i)*18 + ww + j], k9[i*3+j], acc);
      float s = acc / (1.f + __expf(-acc));
      xc[((long)b*DIN + d)*L_ + (h0+hh)*W_ + w0 + ww] = s;
      tout[q][hh][ww] = s;
    }
    __syncthreads();
    #pragma unroll
    for (int q = 0; q < 8; ++q) {
      const int d = d0 + oct*8 + q;
      float s2 = tout[q][t & 15][t >> 4];
      xT[((long)b*DIN + d)*L_ + (w0 + (t>>4))*H_ + h0 + (t & 15)] = s2;
    }
    __syncthreads();
  }
}

// ----------------------------------------------------------- K3: x_dbl proj
// dts_low kept [r][l]; B/C emitted interleaved BCln[(b,k)][l][n] = (B,C)
__global__ __launch_bounds__(256) void k3_xdbl(
    const float* __restrict__ xc, const float* __restrict__ xT,
    const float* __restrict__ xpw, float* __restrict__ dts_low,
    float* __restrict__ BCln) {
  const int bid = blockIdx.x;
  const int lt = bid % 72; const int k = (bid/72) & 3; const int b = bid / 288;
  const int l0 = lt * 32;
  __shared__ float xtile[DIN*32];
  __shared__ float wl[38*193];
  __shared__ float sBC[32*16*2];                // [l][n][{B,C}]
  const float* src = (k & 1) ? xT : xc;
  const bool flip = k >= 2;
  const int t = threadIdx.x;
  for (int idx = t; idx < DIN*32; idx += 256) {
    int d = idx >> 5, j = idx & 31;
    int pos = flip ? (L_-1 - (l0+j)) : (l0+j);
    xtile[d*32 + j] = src[((long)b*DIN + d)*L_ + pos];
  }
  for (int idx = t; idx < 38*DIN; idx += 256) {
    int c = idx / DIN, d = idx % DIN;
    wl[c*193 + d] = xpw[(k*38 + c)*DIN + d];
  }
  __syncthreads();
  for (int u = t; u < 38*8; u += 256) {
    int jq = u & 7, c = u >> 3;
    float4 acc = {0.f,0.f,0.f,0.f};
    for (int d = 0; d < DIN; ++d) {
      float wv = wl[c*193 + d];
      float4 x4 = *((const float4*)&xtile[d*32 + jq*4]);
      acc.x = fmaf(wv, x4.x, acc.x); acc.y = fmaf(wv, x4.y, acc.y);
      acc.z = fmaf(wv, x4.z, acc.z); acc.w = fmaf(wv, x4.w, acc.w);
    }
    if (c < 6) {
      *((float4*)&dts_low[((long)(b*KD + k)*RNK + c)*L_ + l0 + jq*4]) = acc;
    } else if (c < 22) {
      const int n = c - 6;
      sBC[((jq*4+0)*16 + n)*2] = acc.x;
      sBC[((jq*4+1)*16 + n)*2] = acc.y;
      sBC[((jq*4+2)*16 + n)*2] = acc.z;
      sBC[((jq*4+3)*16 + n)*2] = acc.w;
    } else {
      const int n = c - 22;
      sBC[((jq*4+0)*16 + n)*2 + 1] = acc.x;
      sBC[((jq*4+1)*16 + n)*2 + 1] = acc.y;
      sBC[((jq*4+2)*16 + n)*2 + 1] = acc.z;
      sBC[((jq*4+3)*16 + n)*2 + 1] = acc.w;
    }
  }
  __syncthreads();
  const float2* sbc2 = (const float2*)sBC;
  float2* dst = (float2*)BCln + (long)(b*KD + k)*L_*16 + (long)l0*16;
  for (int idx = t; idx < 512; idx += 256) dst[idx] = sbc2[idx];
}

// --------------------------------------------- K4a: chunk-local scan carries
__global__ __launch_bounds__(128, 4) void k4a_carry(
    const float* __restrict__ xc, const float* __restrict__ xT,
    const float* __restrict__ dts_low, const float* __restrict__ BCln,
    const float* __restrict__ dtw_g, const float* __restrict__ dtb_g,
    const float* __restrict__ A_logs, float* __restrict__ carryH,
    float* __restrict__ carryP) {
  const int bid = blockIdx.x;
  const int cc = bid % (NCH-1); const int rest = bid / (NCH-1);
  const int dt = rest % 24; const int k = (rest/24) & 3; const int b = rest / 96;
  const int d0 = dt * 8;
  const int t = threadIdx.x;
  const int g = t >> 4, nj = t & 15;
  __shared__ alignas(16) float2 du[2][8][20];

  const int d = d0 + g;
  const float a = -__expf(A_logs[(k*DIN + d)*NST + nj]);
  float dtw[6];
  #pragma unroll
  for (int r = 0; r < 6; ++r) dtw[r] = dtw_g[(k*DIN + d)*RNK + r];
  const float dtbv = dtb_g[k*DIN + d];
  const float* src  = (k & 1) ? xT : xc;
  const bool flip = k >= 2;
  const float* bcf  = (const float*)((const float2*)BCln + (long)(b*KD + k)*L_*16);
  const float* dtlb = dts_low + (long)(b*KD + k)*RNK*L_;
  const float* ub   = src + ((long)b*DIN + d)*L_;
  const int base = cc * LC;

  float br[16];         // B for current chunk (prefetched across barrier)
  float tD[6], uN;      // raw inputs for next chunk's du

  auto issue_ud = [&](int c2) {
    const int l0 = base + c2*16;
    const int pos = flip ? (L_-1 - (l0+nj)) : (l0+nj);
    uN = ub[pos];
    #pragma unroll
    for (int r = 0; r < 6; ++r) tD[r] = dtlb[r*L_ + l0 + nj];
  };
  auto finish_du = [&](int pbuf) {
    float acc = dtbv;
    #pragma unroll
    for (int r = 0; r < 6; ++r) acc = fmaf(dtw[r], tD[r], acc);
    const float dl = (acc > 20.f) ? acc : log1pf(__expf(acc));
    du[pbuf][g][nj] = make_float2(dl, dl*uN);
  };
  auto issue_b = [&](int c2) {
    const int l0 = base + c2*16;
    #pragma unroll
    for (int j = 0; j < 16; ++j) br[j] = bcf[((l0 + j)*16 + nj)*2];
  };

  issue_ud(0); finish_du(0); issue_b(0);
  __syncthreads();

  float h = 0.f, prod = 1.f;
  for (int c2 = 0; c2 < LC/16; ++c2) {
    const int pb = c2 & 1;
    issue_ud(c2 + 1);                         // next chunk raw du inputs
    #pragma unroll
    for (int m = 0; m < 8; ++m) {
      float4 dd = *((const float4*)&du[pb][g][2*m]);
      float dA0 = __expf(dd.x * a);
      h = fmaf(h, dA0, dd.y * br[2*m]);
      prod *= dA0;
      float dA1 = __expf(dd.z * a);
      h = fmaf(h, dA1, dd.w * br[2*m+1]);
      prod *= dA1;
    }
    finish_du(pb ^ 1);                        // write next du buffer
    issue_b(c2 + 1);                          // drains at the barrier below
    __syncthreads();
  }
  const long s = (long)(b*KD + k)*DIN + d;
  carryH[(s*NCH + cc)*16 + nj] = h;
  carryP[(s*NCH + cc)*16 + nj] = prod;
}

// ------------------------------------------------------ K4b: combine carries
__global__ __launch_bounds__(256) void k4b_combine(
    float* __restrict__ carryH, const float* __restrict__ carryP) {
  const int tid = blockIdx.x*256 + threadIdx.x;   // < 6144*16
  const int n = tid & 15; const long s = tid >> 4;
  float h = 0.f;
  #pragma unroll
  for (int c = 0; c < NCH-1; ++c) {
    const long idx = (s*NCH + c)*16 + n;
    const float ho = carryH[idx];
    const float ap = carryP[idx];
    carryH[idx] = h;
    h = fmaf(h, ap, ho);
  }
  carryH[(s*NCH + (NCH-1))*16 + n] = h;
}

// ----------------------------------------------------- K4c: full scan + y-out
__global__ __launch_bounds__(128, 4) void k4c_scan(
    const float* __restrict__ xc, const float* __restrict__ xT,
    const float* __restrict__ dts_low, const float* __restrict__ BCln,
    const float* __restrict__ dtw_g, const float* __restrict__ dtb_g,
    const float* __restrict__ A_logs, const float* __restrict__ carryH,
    float* __restrict__ bufA, float* __restrict__ bufB) {
  const int bid = blockIdx.x;
  const int cc = bid % NCH; const int rest = bid / NCH;
  const int dt = rest % 24; const int k = (rest/24) & 3; const int b = rest / 96;
  const int d0 = dt * 8;
  const int t = threadIdx.x;
  const int g = t >> 4, nj = t & 15;
  __shared__ alignas(16) float2 du[2][8][20];

  const int d = d0 + g;
  const float a  = -__expf(A_logs[(k*DIN + d)*NST + nj]);
  float dtw[6];
  #pragma unroll
  for (int r = 0; r < 6; ++r) dtw[r] = dtw_g[(k*DIN + d)*RNK + r];
  const float dtbv = dtb_g[k*DIN + d];
  const float* src  = (k & 1) ? xT : xc;
  const bool flip = k >= 2;
  const float2* bcp = (const float2*)BCln + (long)(b*KD + k)*L_*16;
  const float* dtlb = dts_low + (long)(b*KD + k)*RNK*L_;
  const float* ub   = src + ((long)b*DIN + d)*L_;
  float* yb = ((k & 1) ? bufB : bufA) + (((long)b*2 + (k>>1))*DIN + d)*L_;
  const long s = (long)(b*KD + k)*DIN + d;
  const int base = cc * LC;

  float2 bc[16];
  float tD[6], uN;

  auto issue_ud = [&](int c2) {
    const int l0 = base + c2*16;
    const int pos = flip ? (L_-1 - (l0+nj)) : (l0+nj);
    uN = ub[pos];
    #pragma unroll
    for (int r = 0; r < 6; ++r) tD[r] = dtlb[r*L_ + l0 + nj];
  };
  auto finish_du = [&](int pbuf) {
    float acc = dtbv;
    #pragma unroll
    for (int r = 0; r < 6; ++r) acc = fmaf(dtw[r], tD[r], acc);
    const float dl = (acc > 20.f) ? acc : log1pf(__expf(acc));
    du[pbuf][g][nj] = make_float2(dl, dl*uN);
  };
  auto issue_bc = [&](int c2) {
    const int l0 = base + c2*16;
    #pragma unroll
    for (int j = 0; j < 16; ++j) bc[j] = bcp[(l0 + j)*16 + nj];
  };

  issue_ud(0); finish_du(0); issue_bc(0);
  __syncthreads();

  float h = carryH[(s*NCH + cc)*16 + nj];
  for (int c2 = 0; c2 < LC/16; ++c2) {
    const int pb = c2 & 1;
    issue_ud(c2 + 1);
    float p[16];
    #pragma unroll
    for (int m = 0; m < 8; ++m) {
      float4 dd = *((const float4*)&du[pb][g][2*m]);
      float2 b0 = bc[2*m], b1 = bc[2*m+1];
      float dA0 = __expf(dd.x * a);
      h = fmaf(h, dA0, dd.y * b0.x);
      p[2*m] = h * b0.y;
      float dA1 = __expf(dd.z * a);
      h = fmaf(h, dA1, dd.w * b1.x);
      p[2*m+1] = h * b1.y;
    }
    // hybrid butterfly transpose-reduce: xor1/xor2 on VALU (DPP), xor4/8 on DS
    #pragma unroll
    for (int kk = 0; kk < 4; ++kk) {
      const int m = 1 << kk;
      const bool bb = (nj & m) != 0;
      #pragma unroll
      for (int ii = 0; ii < (16 >> (kk+1)); ++ii) {
        float x0 = p[2*ii], x1 = p[2*ii+1];
        float send = bb ? x0 : x1;
        float keep = bb ? x1 : x0;
        float got;
        if (kk == 0)      got = dpp_xor1(send);
        else if (kk == 1) got = dpp_xor2(send);
        else              got = __shfl_xor(send, m, 64);
        p[ii] = keep + got;
      }
    }
    const int l0 = base + c2*16;
    const int pos = flip ? (L_-1 - (l0+nj)) : (l0+nj);
    yb[pos] = p[0];                           // D*u folded into k5a
    finish_du(pb ^ 1);
    issue_bc(c2 + 1);                         // drains at barrier: free prefetch
    __syncthreads();
  }
}

// ------------------------------------------------------------ K5a: cross-merge
// ym = bufA0+bufA1+bufB0+bufB1 (+ (D0+D2)*xc + (D1+D3)*xT skip terms)
__global__ __launch_bounds__(256) void k5a_merge(
    const float* __restrict__ bufA, const float* __restrict__ bufB,
    const float* __restrict__ xc, const float* __restrict__ xT,
    const float* __restrict__ Ds_g, float* __restrict__ ym) {
  const int bid = blockIdx.x;
  const int dc = bid % 6; const int tile = (bid/6) % 9; const int b = bid / 54;
  const int h0 = (tile/3)*16, w0 = (tile%3)*16, d0 = dc*32;
  __shared__ float acc[8644];
  __shared__ float d02[32], d13[32];
  const int t = threadIdx.x;
  if (t < 32) {
    d02[t] = Ds_g[0*DIN + d0 + t] + Ds_g[2*DIN + d0 + t];
    d13[t] = Ds_g[1*DIN + d0 + t] + Ds_g[3*DIN + d0 + t];
  }
  __syncthreads();
  for (int idx = t; idx < 8192; idx += 256) {   // lanes along w (bufA, xc)
    int w = idx & 15, hh = (idx >> 4) & 15, ds = idx >> 8;
    long pos = (long)(h0+hh)*W_ + w0 + w;
    long off = ((long)b*DIN + d0+ds)*L_ + pos;
    float v = bufA[(((long)b*2 + 0)*DIN + d0+ds)*L_ + pos]
            + bufA[(((long)b*2 + 1)*DIN + d0+ds)*L_ + pos]
            + d02[ds]*xc[off];
    acc[hh*541 + w*33 + ds] = v;
  }
  __syncthreads();
  for (int idx = t; idx < 8192; idx += 256) {   // lanes along h (bufB, xT)
    int hh = idx & 15, w = (idx >> 4) & 15, ds = idx >> 8;
    long m = (long)(w0+w)*H_ + h0 + hh;
    long off = ((long)b*DIN + d0+ds)*L_ + m;
    float v = bufB[(((long)b*2 + 0)*DIN + d0+ds)*L_ + m]
            + bufB[(((long)b*2 + 1)*DIN + d0+ds)*L_ + m]
            + d13[ds]*xT[off];
    acc[hh*541 + w*33 + ds] += v;
  }
  __syncthreads();
  for (int idx = t; idx < 8192; idx += 256) {   // lanes along d (write)
    int ds = idx & 31, w = (idx >> 5) & 15, hh = idx >> 9;
    ym[((long)b*L_ + (h0+hh)*W_ + w0+w)*DIN + d0 + ds] = acc[hh*541 + w*33 + ds];
  }
}

// ----------------------------------------- K5b: LayerNorm + gate + out_proj
__global__ __launch_bounds__(256) void k5b_out(
    const float* __restrict__ ym, const float* __restrict__ zs,
    const float* __restrict__ lnw, const float* __restrict__ lnb,
    const float* __restrict__ wo, float* __restrict__ out) {
  const int bid = blockIdx.x;
  const int ch = bid & 1; const int lt = (bid >> 1) % 72; const int b = bid / 144;
  const int l0 = lt * 32;
  const int c0 = ch * 48;
  __shared__ float yt[DIN*33];
  __shared__ float wt[DIN*48];
  __shared__ float mu_s[32], rs_s[32];
  const int t = threadIdx.x;
  for (int idx = t; idx < 32*DIN; idx += 256) {
    int dd = idx % DIN, l = idx / DIN;
    yt[dd*33 + l] = ym[((long)b*L_ + l0 + l)*DIN + dd];
  }
  for (int idx = t; idx < DIN*48; idx += 256) {
    int cc = idx % 48, dd = idx / 48;
    wt[dd*48 + cc] = wo[(c0 + cc)*DIN + dd];
  }
  __syncthreads();
  {
    int l = t >> 3, s = t & 7;
    float sum = 0.f, sq = 0.f;
    for (int dd = s; dd < DIN; dd += 8) {
      float v = yt[dd*33 + l]; sum += v; sq = fmaf(v, v, sq);
    }
    #pragma unroll
    for (int o = 1; o < 8; o <<= 1) { sum += __shfl_xor(sum, o, 64); sq += __shfl_xor(sq, o, 64); }
    if (s == 0) {
      float mu = sum * (1.f/192.f);
      mu_s[l] = mu;
      rs_s[l] = rsqrtf(fmaxf(sq * (1.f/192.f) - mu*mu, 0.f) + 1e-5f);
    }
  }
  __syncthreads();
  for (int idx = t; idx < 32*DIN; idx += 256) {
    int dd = idx % DIN, l = idx / DIN;
    float v = yt[dd*33 + l];
    v = (v - mu_s[l]) * rs_s[l] * lnw[dd] + lnb[dd];
    v *= zs[((long)b*L_ + l0 + l)*DIN + dd];
    yt[dd*33 + l] = v;
  }
  __syncthreads();
  for (int u = t; u < 24*16; u += 256) {
    int cp = u % 24, lp = u / 24;
    int cc = cp*2, l = lp*2;
    float a00=0.f, a01=0.f, a10=0.f, a11=0.f;
    for (int dd = 0; dd < DIN; ++dd) {
      float2 wv = *((const float2*)&wt[dd*48 + cc]);
      float2 yv = *((const float2*)&yt[dd*33 + l]);
      a00 = fmaf(wv.x, yv.x, a00); a01 = fmaf(wv.y, yv.x, a01);
      a10 = fmaf(wv.x, yv.y, a10); a11 = fmaf(wv.y, yv.y, a11);
    }
    long ob = ((long)b*L_ + l0 + l)*DM + c0 + cc;
    *((float2*)&out[ob])      = make_float2(a00, a01);
    *((float2*)&out[ob + DM]) = make_float2(a10, a11);
  }
}

// ------------------------------------------------------------------- launcher
extern "C" void kernel_launch(void* const* d_in, const int* in_sizes, int n_in,
                              void* d_out, int out_size, void* d_ws, size_t ws_size,
                              hipStream_t stream) {
  (void)in_sizes; (void)n_in; (void)out_size; (void)ws_size;
  const float* x      = (const float*)d_in[0];
  const float* w_in   = (const float*)d_in[1];
  const float* conv_w = (const float*)d_in[2];
  const float* conv_b = (const float*)d_in[3];
  const float* xpw    = (const float*)d_in[4];
  const float* dtw    = (const float*)d_in[5];
  const float* dtb    = (const float*)d_in[6];
  const float* A_logs = (const float*)d_in[7];
  const float* Ds     = (const float*)d_in[8];
  const float* lnw    = (const float*)d_in[9];
  const float* lnb    = (const float*)d_in[10];
  const float* wout   = (const float*)d_in[11];
  float* out = (float*)d_out;
  float* ws  = (float*)d_ws;

  const long SZ_BLD = (long)B_*L_*DIN;          // 3,538,944 floats
  float* xc_pre  = ws;                          // (B,L,Din) [reused: carries, then ym]
  float* z_silu  = ws + SZ_BLD;
  float* xc      = ws + 2*SZ_BLD;
  float* xT      = ws + 3*SZ_BLD;
  float* dts_low = ws + 4*SZ_BLD;
  float* BCln    = dts_low + (long)B_*KD*RNK*L_;      // (B,K,L,16) float2
  float* bufA    = BCln + (long)B_*KD*L_*16*2;        // (B,2,Din,L)
  float* bufB    = bufA + (long)B_*2*DIN*L_;
  float* carryH  = xc_pre;                      // aliases xc_pre (dead after K2)
  float* carryP  = xc_pre + (long)6144*NCH*16;
  float* ym      = xc_pre;                      // aliases (carries dead after K4c)

  k1_inproj  <<<(B_*L_)/16,        256, 0, stream>>>(x, w_in, xc_pre, z_silu);
  k2_conv    <<<B_*6*9,            256, 0, stream>>>(xc_pre, conv_w, conv_b, xc, xT);
  k3_xdbl    <<<B_*KD*72,          256, 0, stream>>>(xc, xT, xpw, dts_low, BCln);
  k4a_carry  <<<B_*KD*24*(NCH-1),  128, 0, stream>>>(xc, xT, dts_low, BCln, dtw, dtb,
                                                     A_logs, carryH, carryP);
  k4b_combine<<<(6144*16)/256,     256, 0, stream>>>(carryH, carryP);
  k4c_scan   <<<B_*KD*24*NCH,      128, 0, stream>>>(xc, xT, dts_low, BCln, dtw, dtb,
                                                     A_logs, carryH, bufA, bufB);
  k5a_merge  <<<B_*9*6,            256, 0, stream>>>(bufA, bufB, xc, xT, Ds, ym);
  k5b_out    <<<B_*72*2,           256, 0, stream>>>(ym, z_silu, lnw, lnb, wout, out);
}

// Round 6
// 509.172 us; speedup vs baseline: 1.0590x; 1.0590x over previous
//
#include <hip/hip_runtime.h>
#include <hip/hip_bf16.h>

// SS2D fused pipeline for MI355X (gfx950). All fp32.
// K1 in_proj(+silu z) -> K2 dwconv3x3+silu(+transposed copy) -> K3 x_dbl proj
// (dts_low + separate Bln/Cln [l][n]) -> K4a chunk-local carries -> K4b combine
// -> K4c full scan -- K4a/K4c are barrier-free: wave = 16d x 4q lanes, 4 n-states
// in registers per lane, quad-DPP broadcast for delta, DPP-xor reduce for y.
// -> K5a cross-merge (+D*u skip) -> K5b LayerNorm+gate+out_proj.

#define B_   8
#define H_   48
#define W_   48
#define DM   96
#define DIN  192
#define NST  16
#define RNK  6
#define KD   4
#define L_   (H_*W_)      // 2304
#define NCH  8
#define LC   (L_/NCH)     // 288 = 18 sub-chunks of 16

__device__ __forceinline__ float dpp_xor1(float v) {   // quad_perm [1,0,3,2]
  return __int_as_float(__builtin_amdgcn_update_dpp(
      0, __float_as_int(v), 0xB1, 0xf, 0xf, false));
}
__device__ __forceinline__ float dpp_xor2(float v) {   // quad_perm [2,3,0,1]
  return __int_as_float(__builtin_amdgcn_update_dpp(
      0, __float_as_int(v), 0x4E, 0xf, 0xf, false));
}
template<int Q> __device__ __forceinline__ float qbcast(float v) { // quad lane Q
  return __int_as_float(__builtin_amdgcn_update_dpp(
      0, __float_as_int(v), Q*0x55, 0xf, 0xf, false));
}

// ---------------------------------------------------------------- K1: in_proj
__global__ __launch_bounds__(256) void k1_inproj(
    const float* __restrict__ x, const float* __restrict__ w,
    float* __restrict__ xc_pre, float* __restrict__ z_silu) {
  __shared__ float xs[16][100];
  const int t = threadIdx.x;
  const long row0 = (long)blockIdx.x * 16;
  for (int idx = t; idx < 16*96; idx += 256) {
    int r = idx / 96, c = idx % 96;
    xs[r][c] = x[(row0 + r)*96 + c];
  }
  __syncthreads();
  for (int u = t; u < 2*DIN; u += 256) {
    float acc[16];
    #pragma unroll
    for (int r = 0; r < 16; ++r) acc[r] = 0.f;
    const float4* wrow = (const float4*)(w + u*96);
    #pragma unroll 4
    for (int cq = 0; cq < 24; ++cq) {
      float4 w4 = wrow[cq];
      #pragma unroll
      for (int r = 0; r < 16; ++r) {
        float4 x4 = *((const float4*)&xs[r][cq*4]);
        acc[r] = fmaf(w4.x,x4.x, fmaf(w4.y,x4.y, fmaf(w4.z,x4.z, fmaf(w4.w,x4.w, acc[r]))));
      }
    }
    if (u < DIN) {
      #pragma unroll
      for (int r = 0; r < 16; ++r) xc_pre[(row0 + r)*DIN + u] = acc[r];
    } else {
      #pragma unroll
      for (int r = 0; r < 16; ++r) {
        float v = acc[r];
        z_silu[(row0 + r)*DIN + (u - DIN)] = v / (1.f + __expf(-v));
      }
    }
  }
}

// ------------------------------------------------- K2: depthwise conv + silu
__global__ __launch_bounds__(256) void k2_conv(
    const float* __restrict__ xc_pre, const float* __restrict__ cw,
    const float* __restrict__ cb, float* __restrict__ xc, float* __restrict__ xT) {
  const int bid = blockIdx.x;
  const int tile = bid % 9; const int dc = (bid/9) % 6; const int b = bid / 54;
  const int h0 = (tile/3)*16, w0 = (tile%3)*16, d0 = dc*32;
  __shared__ float tin[32*325];
  __shared__ float tout[8][16][17];
  const int t = threadIdx.x;
  for (int idx = t; idx < 32*18*18; idx += 256) {
    int d2 = idx & 31; int rest = idx >> 5; int ww = rest % 18; int hh = rest / 18;
    int h = h0 + hh - 1, w = w0 + ww - 1;
    float v = 0.f;
    if (h >= 0 && h < H_ && w >= 0 && w < W_)
      v = xc_pre[((long)b*L_ + h*W_ + w)*DIN + d0 + d2];
    tin[d2*325 + hh*18 + ww] = v;
  }
  __syncthreads();
  const int hh = t >> 4, ww = t & 15;
  for (int oct = 0; oct < 4; ++oct) {
    #pragma unroll
    for (int q = 0; q < 8; ++q) {
      const int d2 = oct*8 + q;
      const int d = d0 + d2;
      float acc = cb[d];
      const float* k9 = &cw[d*9];
      const float* base = &tin[d2*325];
      #pragma unroll
      for (int i = 0; i < 3; ++i)
        #pragma unroll
        for (int j = 0; j < 3; ++j)
          acc = fmaf(base[(hh+i)*18 + ww + j], k9[i*3+j], acc);
      float s = acc / (1.f + __expf(-acc));
      xc[((long)b*DIN + d)*L_ + (h0+hh)*W_ + w0 + ww] = s;
      tout[q][hh][ww] = s;
    }
    __syncthreads();
    #pragma unroll
    for (int q = 0; q < 8; ++q) {
      const int d = d0 + oct*8 + q;
      float s2 = tout[q][t & 15][t >> 4];
      xT[((long)b*DIN + d)*L_ + (w0 + (t>>4))*H_ + h0 + (t & 15)] = s2;
    }
    __syncthreads();
  }
}

// ----------------------------------------------------------- K3: x_dbl proj
// dts_low [r][l] (traversal order); B,C -> separate Bln/Cln [(b,k)][l][16]
__global__ __launch_bounds__(256) void k3_xdbl(
    const float* __restrict__ xc, const float* __restrict__ xT,
    const float* __restrict__ xpw, float* __restrict__ dts_low,
    float* __restrict__ Bln, float* __restrict__ Cln) {
  const int bid = blockIdx.x;
  const int lt = bid % 72; const int k = (bid/72) & 3; const int b = bid / 288;
  const int l0 = lt * 32;
  __shared__ float xtile[DIN*32];
  __shared__ float wl[38*193];
  __shared__ float sB[32][17];
  __shared__ float sC[32][17];
  const float* src = (k & 1) ? xT : xc;
  const bool flip = k >= 2;
  const int t = threadIdx.x;
  for (int idx = t; idx < DIN*32; idx += 256) {
    int d = idx >> 5, j = idx & 31;
    int pos = flip ? (L_-1 - (l0+j)) : (l0+j);
    xtile[d*32 + j] = src[((long)b*DIN + d)*L_ + pos];
  }
  for (int idx = t; idx < 38*DIN; idx += 256) {
    int c = idx / DIN, d = idx % DIN;
    wl[c*193 + d] = xpw[(k*38 + c)*DIN + d];
  }
  __syncthreads();
  for (int u = t; u < 38*8; u += 256) {
    int jq = u & 7, c = u >> 3;
    float4 acc = {0.f,0.f,0.f,0.f};
    for (int d = 0; d < DIN; ++d) {
      float wv = wl[c*193 + d];
      float4 x4 = *((const float4*)&xtile[d*32 + jq*4]);
      acc.x = fmaf(wv, x4.x, acc.x); acc.y = fmaf(wv, x4.y, acc.y);
      acc.z = fmaf(wv, x4.z, acc.z); acc.w = fmaf(wv, x4.w, acc.w);
    }
    if (c < 6) {
      *((float4*)&dts_low[((long)(b*KD + k)*RNK + c)*L_ + l0 + jq*4]) = acc;
    } else if (c < 22) {
      const int n = c - 6;
      sB[jq*4+0][n] = acc.x; sB[jq*4+1][n] = acc.y;
      sB[jq*4+2][n] = acc.z; sB[jq*4+3][n] = acc.w;
    } else {
      const int n = c - 22;
      sC[jq*4+0][n] = acc.x; sC[jq*4+1][n] = acc.y;
      sC[jq*4+2][n] = acc.z; sC[jq*4+3][n] = acc.w;
    }
  }
  __syncthreads();
  float* Bdst = Bln + (long)(b*KD + k)*L_*NST + (long)l0*NST;
  float* Cdst = Cln + (long)(b*KD + k)*L_*NST + (long)l0*NST;
  for (int idx = t; idx < 512; idx += 256) {
    int l = idx >> 4, n = idx & 15;
    Bdst[idx] = sB[l][n];
    Cdst[idx] = sC[l][n];
  }
}

// --------------------------------------------- K4a: chunk-local scan carries
// barrier-free: wave = 16 d x 4 q lanes; lane holds n = q*4..q*4+3 in regs.
__global__ __launch_bounds__(256) void k4a_carry(
    const float* __restrict__ xc, const float* __restrict__ xT,
    const float* __restrict__ dts_low, const float* __restrict__ Bln,
    const float* __restrict__ dtw_g, const float* __restrict__ dtb_g,
    const float* __restrict__ A_logs, float* __restrict__ carryH,
    float* __restrict__ carryP) {
  const int t = threadIdx.x;
  const int W = blockIdx.x*4 + (t >> 6);
  const int lane = t & 63;
  const int dloc = lane >> 2, q = lane & 3;
  const int cc = W % (NCH-1); const int r = W / (NCH-1);
  const int dg = r % 12; const int k = (r/12) & 3; const int b = r / 48;
  const int d = dg*16 + dloc;
  const bool flip = k >= 2;

  const float4 al = *(const float4*)&A_logs[(k*DIN + d)*NST + q*4];
  const float a0 = -__expf(al.x), a1 = -__expf(al.y),
              a2 = -__expf(al.z), a3 = -__expf(al.w);
  float dtw[6];
  #pragma unroll
  for (int r2 = 0; r2 < 6; ++r2) dtw[r2] = dtw_g[(k*DIN + d)*RNK + r2];
  const float dtbv = dtb_g[k*DIN + d];
  const float* ub   = ((k & 1) ? xT : xc) + ((long)b*DIN + d)*L_;
  const float* dtlb = dts_low + (long)(b*KD + k)*RNK*L_;
  const float* Bp   = Bln + (long)(b*KD + k)*L_*NST;
  const long s = (long)(b*KD + k)*DIN + d;
  const int base = cc*LC;

  float h0=0.f,h1=0.f,h2=0.f,h3=0.f, p0=1.f,p1=1.f,p2=1.f,p3=1.f;
  for (int c16 = 0; c16 < LC/16; ++c16) {
    const int l0 = base + c16*16;
    float u4[4];
    if (!flip) {
      float4 uu = *(const float4*)&ub[l0 + q*4];
      u4[0]=uu.x; u4[1]=uu.y; u4[2]=uu.z; u4[3]=uu.w;
    } else {
      float4 uu = *(const float4*)&ub[L_-4 - l0 - q*4];
      u4[0]=uu.w; u4[1]=uu.z; u4[2]=uu.y; u4[3]=uu.x;
    }
    float acc[4] = {dtbv, dtbv, dtbv, dtbv};
    #pragma unroll
    for (int r2 = 0; r2 < 6; ++r2) {
      float4 dv = *(const float4*)&dtlb[r2*L_ + l0 + q*4];
      acc[0] = fmaf(dtw[r2], dv.x, acc[0]);
      acc[1] = fmaf(dtw[r2], dv.y, acc[1]);
      acc[2] = fmaf(dtw[r2], dv.z, acc[2]);
      acc[3] = fmaf(dtw[r2], dv.w, acc[3]);
    }
    float dl4[4], du4[4];
    #pragma unroll
    for (int i = 0; i < 4; ++i) {
      float dl = (acc[i] > 20.f) ? acc[i] : log1pf(__expf(acc[i]));
      dl4[i] = dl; du4[i] = dl * u4[i];
    }
#define CAR_STEP(QQ, II) { \
      const int j = QQ*4 + II; \
      const float dlv = qbcast<QQ>(dl4[II]); \
      const float duv = qbcast<QQ>(du4[II]); \
      const float4 B4 = *(const float4*)&Bp[(l0+j)*NST + q*4]; \
      float e; \
      e = __expf(dlv*a0); h0 = fmaf(h0, e, duv*B4.x); p0 *= e; \
      e = __expf(dlv*a1); h1 = fmaf(h1, e, duv*B4.y); p1 *= e; \
      e = __expf(dlv*a2); h2 = fmaf(h2, e, duv*B4.z); p2 *= e; \
      e = __expf(dlv*a3); h3 = fmaf(h3, e, duv*B4.w); p3 *= e; }
    CAR_STEP(0,0) CAR_STEP(0,1) CAR_STEP(0,2) CAR_STEP(0,3)
    CAR_STEP(1,0) CAR_STEP(1,1) CAR_STEP(1,2) CAR_STEP(1,3)
    CAR_STEP(2,0) CAR_STEP(2,1) CAR_STEP(2,2) CAR_STEP(2,3)
    CAR_STEP(3,0) CAR_STEP(3,1) CAR_STEP(3,2) CAR_STEP(3,3)
#undef CAR_STEP
  }
  *(float4*)&carryH[(s*NCH + cc)*NST + q*4] = make_float4(h0,h1,h2,h3);
  *(float4*)&carryP[(s*NCH + cc)*NST + q*4] = make_float4(p0,p1,p2,p3);
}

// ------------------------------------------------------ K4b: combine carries
__global__ __launch_bounds__(256) void k4b_combine(
    float* __restrict__ carryH, const float* __restrict__ carryP) {
  const int tid = blockIdx.x*256 + threadIdx.x;   // < 6144*16
  const int n = tid & 15; const long s = tid >> 4;
  float h = 0.f;
  #pragma unroll
  for (int c = 0; c < NCH-1; ++c) {
    const long idx = (s*NCH + c)*16 + n;
    const float ho = carryH[idx];
    const float ap = carryP[idx];
    carryH[idx] = h;
    h = fmaf(h, ap, ho);
  }
  carryH[(s*NCH + (NCH-1))*16 + n] = h;
}

// ----------------------------------------------------- K4c: full scan + y-out
__global__ __launch_bounds__(256) void k4c_scan(
    const float* __restrict__ xc, const float* __restrict__ xT,
    const float* __restrict__ dts_low, const float* __restrict__ Bln,
    const float* __restrict__ Cln, const float* __restrict__ dtw_g,
    const float* __restrict__ dtb_g, const float* __restrict__ A_logs,
    const float* __restrict__ carryH, float* __restrict__ bufA,
    float* __restrict__ bufB) {
  const int t = threadIdx.x;
  const int W = blockIdx.x*4 + (t >> 6);
  const int lane = t & 63;
  const int dloc = lane >> 2, q = lane & 3;
  const int cc = W & 7; const int r = W >> 3;
  const int dg = r % 12; const int k = (r/12) & 3; const int b = r / 48;
  const int d = dg*16 + dloc;
  const bool flip = k >= 2;

  const float4 al = *(const float4*)&A_logs[(k*DIN + d)*NST + q*4];
  const float a0 = -__expf(al.x), a1 = -__expf(al.y),
              a2 = -__expf(al.z), a3 = -__expf(al.w);
  float dtw[6];
  #pragma unroll
  for (int r2 = 0; r2 < 6; ++r2) dtw[r2] = dtw_g[(k*DIN + d)*RNK + r2];
  const float dtbv = dtb_g[k*DIN + d];
  const float* ub   = ((k & 1) ? xT : xc) + ((long)b*DIN + d)*L_;
  const float* dtlb = dts_low + (long)(b*KD + k)*RNK*L_;
  const float* Bp   = Bln + (long)(b*KD + k)*L_*NST;
  const float* Cp   = Cln + (long)(b*KD + k)*L_*NST;
  float* yb = ((k & 1) ? bufB : bufA) + (((long)b*2 + (k>>1))*DIN + d)*L_;
  const long s = (long)(b*KD + k)*DIN + d;

  float4 hv = *(const float4*)&carryH[(s*NCH + cc)*NST + q*4];
  float h0 = hv.x, h1 = hv.y, h2 = hv.z, h3 = hv.w;
  const int base = cc*LC;

  for (int c16 = 0; c16 < LC/16; ++c16) {
    const int l0 = base + c16*16;
    float u4[4];
    if (!flip) {
      float4 uu = *(const float4*)&ub[l0 + q*4];
      u4[0]=uu.x; u4[1]=uu.y; u4[2]=uu.z; u4[3]=uu.w;
    } else {
      float4 uu = *(const float4*)&ub[L_-4 - l0 - q*4];
      u4[0]=uu.w; u4[1]=uu.z; u4[2]=uu.y; u4[3]=uu.x;
    }
    float acc[4] = {dtbv, dtbv, dtbv, dtbv};
    #pragma unroll
    for (int r2 = 0; r2 < 6; ++r2) {
      float4 dv = *(const float4*)&dtlb[r2*L_ + l0 + q*4];
      acc[0] = fmaf(dtw[r2], dv.x, acc[0]);
      acc[1] = fmaf(dtw[r2], dv.y, acc[1]);
      acc[2] = fmaf(dtw[r2], dv.z, acc[2]);
      acc[3] = fmaf(dtw[r2], dv.w, acc[3]);
    }
    float dl4[4], du4[4];
    #pragma unroll
    for (int i = 0; i < 4; ++i) {
      float dl = (acc[i] > 20.f) ? acc[i] : log1pf(__expf(acc[i]));
      dl4[i] = dl; du4[i] = dl * u4[i];
    }
    float y[16];
#define SCAN_STEP(QQ, II) { \
      const int j = QQ*4 + II; \
      const float dlv = qbcast<QQ>(dl4[II]); \
      const float duv = qbcast<QQ>(du4[II]); \
      const float4 B4 = *(const float4*)&Bp[(l0+j)*NST + q*4]; \
      const float4 C4 = *(const float4*)&Cp[(l0+j)*NST + q*4]; \
      h0 = fmaf(h0, __expf(dlv*a0), duv*B4.x); \
      h1 = fmaf(h1, __expf(dlv*a1), duv*B4.y); \
      h2 = fmaf(h2, __expf(dlv*a2), duv*B4.z); \
      h3 = fmaf(h3, __expf(dlv*a3), duv*B4.w); \
      float yv = fmaf(h3, C4.w, fmaf(h2, C4.z, fmaf(h1, C4.y, h0*C4.x))); \
      yv += dpp_xor1(yv); \
      yv += dpp_xor2(yv); \
      y[j] = yv; }
    SCAN_STEP(0,0) SCAN_STEP(0,1) SCAN_STEP(0,2) SCAN_STEP(0,3)
    SCAN_STEP(1,0) SCAN_STEP(1,1) SCAN_STEP(1,2) SCAN_STEP(1,3)
    SCAN_STEP(2,0) SCAN_STEP(2,1) SCAN_STEP(2,2) SCAN_STEP(2,3)
    SCAN_STEP(3,0) SCAN_STEP(3,1) SCAN_STEP(3,2) SCAN_STEP(3,3)
#undef SCAN_STEP
    if (q == 0) {
      if (!flip) {
        #pragma unroll
        for (int m = 0; m < 4; ++m)
          *(float4*)&yb[l0 + 4*m] =
              make_float4(y[4*m], y[4*m+1], y[4*m+2], y[4*m+3]);
      } else {
        #pragma unroll
        for (int m = 0; m < 4; ++m)
          *(float4*)&yb[L_-4 - l0 - 4*m] =
              make_float4(y[4*m+3], y[4*m+2], y[4*m+1], y[4*m]);
      }
    }
  }
}

// ------------------------------------------------------------ K5a: cross-merge
// ym = bufA0+bufA1+bufB0+bufB1 (+ (D0+D2)*xc + (D1+D3)*xT skip terms)
__global__ __launch_bounds__(256) void k5a_merge(
    const float* __restrict__ bufA, const float* __restrict__ bufB,
    const float* __restrict__ xc, const float* __restrict__ xT,
    const float* __restrict__ Ds_g, float* __restrict__ ym) {
  const int bid = blockIdx.x;
  const int dc = bid % 6; const int tile = (bid/6) % 9; const int b = bid / 54;
  const int h0 = (tile/3)*16, w0 = (tile%3)*16, d0 = dc*32;
  __shared__ float acc[8644];
  __shared__ float d02[32], d13[32];
  const int t = threadIdx.x;
  if (t < 32) {
    d02[t] = Ds_g[0*DIN + d0 + t] + Ds_g[2*DIN + d0 + t];
    d13[t] = Ds_g[1*DIN + d0 + t] + Ds_g[3*DIN + d0 + t];
  }
  __syncthreads();
  for (int idx = t; idx < 8192; idx += 256) {   // lanes along w (bufA, xc)
    int w = idx & 15, hh = (idx >> 4) & 15, ds = idx >> 8;
    long pos = (long)(h0+hh)*W_ + w0 + w;
    long off = ((long)b*DIN + d0+ds)*L_ + pos;
    float v = bufA[(((long)b*2 + 0)*DIN + d0+ds)*L_ + pos]
            + bufA[(((long)b*2 + 1)*DIN + d0+ds)*L_ + pos]
            + d02[ds]*xc[off];
    acc[hh*541 + w*33 + ds] = v;
  }
  __syncthreads();
  for (int idx = t; idx < 8192; idx += 256) {   // lanes along h (bufB, xT)
    int hh = idx & 15, w = (idx >> 4) & 15, ds = idx >> 8;
    long m = (long)(w0+w)*H_ + h0 + hh;
    long off = ((long)b*DIN + d0+ds)*L_ + m;
    float v = bufB[(((long)b*2 + 0)*DIN + d0+ds)*L_ + m]
            + bufB[(((long)b*2 + 1)*DIN + d0+ds)*L_ + m]
            + d13[ds]*xT[off];
    acc[hh*541 + w*33 + ds] += v;
  }
  __syncthreads();
  for (int idx = t; idx < 8192; idx += 256) {   // lanes along d (write)
    int ds = idx & 31, w = (idx >> 5) & 15, hh = idx >> 9;
    ym[((long)b*L_ + (h0+hh)*W_ + w0+w)*DIN + d0 + ds] = acc[hh*541 + w*33 + ds];
  }
}

// ----------------------------------------- K5b: LayerNorm + gate + out_proj
__global__ __launch_bounds__(256) void k5b_out(
    const float* __restrict__ ym, const float* __restrict__ zs,
    const float* __restrict__ lnw, const float* __restrict__ lnb,
    const float* __restrict__ wo, float* __restrict__ out) {
  const int bid = blockIdx.x;
  const int ch = bid & 1; const int lt = (bid >> 1) % 72; const int b = bid / 144;
  const int l0 = lt * 32;
  const int c0 = ch * 48;
  __shared__ float yt[DIN*33];
  __shared__ float wt[DIN*48];
  __shared__ float mu_s[32], rs_s[32];
  const int t = threadIdx.x;
  for (int idx = t; idx < 32*DIN; idx += 256) {
    int dd = idx % DIN, l = idx / DIN;
    yt[dd*33 + l] = ym[((long)b*L_ + l0 + l)*DIN + dd];
  }
  for (int idx = t; idx < DIN*48; idx += 256) {
    int cc = idx % 48, dd = idx / 48;
    wt[dd*48 + cc] = wo[(c0 + cc)*DIN + dd];
  }
  __syncthreads();
  {
    int l = t >> 3, s = t & 7;
    float sum = 0.f, sq = 0.f;
    for (int dd = s; dd < DIN; dd += 8) {
      float v = yt[dd*33 + l]; sum += v; sq = fmaf(v, v, sq);
    }
    #pragma unroll
    for (int o = 1; o < 8; o <<= 1) { sum += __shfl_xor(sum, o, 64); sq += __shfl_xor(sq, o, 64); }
    if (s == 0) {
      float mu = sum * (1.f/192.f);
      mu_s[l] = mu;
      rs_s[l] = rsqrtf(fmaxf(sq * (1.f/192.f) - mu*mu, 0.f) + 1e-5f);
    }
  }
  __syncthreads();
  for (int idx = t; idx < 32*DIN; idx += 256) {
    int dd = idx % DIN, l = idx / DIN;
    float v = yt[dd*33 + l];
    v = (v - mu_s[l]) * rs_s[l] * lnw[dd] + lnb[dd];
    v *= zs[((long)b*L_ + l0 + l)*DIN + dd];
    yt[dd*33 + l] = v;
  }
  __syncthreads();
  for (int u = t; u < 24*16; u += 256) {
    int cp = u % 24, lp = u / 24;
    int cc = cp*2, l = lp*2;
    float a00=0.f, a01=0.f, a10=0.f, a11=0.f;
    for (int dd = 0; dd < DIN; ++dd) {
      float2 wv = *((const float2*)&wt[dd*48 + cc]);
      float2 yv = *((const float2*)&yt[dd*33 + l]);
      a00 = fmaf(wv.x, yv.x, a00); a01 = fmaf(wv.y, yv.x, a01);
      a10 = fmaf(wv.x, yv.y, a10); a11 = fmaf(wv.y, yv.y, a11);
    }
    long ob = ((long)b*L_ + l0 + l)*DM + c0 + cc;
    *((float2*)&out[ob])      = make_float2(a00, a01);
    *((float2*)&out[ob + DM]) = make_float2(a10, a11);
  }
}

// ------------------------------------------------------------------- launcher
extern "C" void kernel_launch(void* const* d_in, const int* in_sizes, int n_in,
                              void* d_out, int out_size, void* d_ws, size_t ws_size,
                              hipStream_t stream) {
  (void)in_sizes; (void)n_in; (void)out_size; (void)ws_size;
  const float* x      = (const float*)d_in[0];
  const float* w_in   = (const float*)d_in[1];
  const float* conv_w = (const float*)d_in[2];
  const float* conv_b = (const float*)d_in[3];
  const float* xpw    = (const float*)d_in[4];
  const float* dtw    = (const float*)d_in[5];
  const float* dtb    = (const float*)d_in[6];
  const float* A_logs = (const float*)d_in[7];
  const float* Ds     = (const float*)d_in[8];
  const float* lnw    = (const float*)d_in[9];
  const float* lnb    = (const float*)d_in[10];
  const float* wout   = (const float*)d_in[11];
  float* out = (float*)d_out;
  float* ws  = (float*)d_ws;

  const long SZ_BLD = (long)B_*L_*DIN;          // 3,538,944 floats
  float* xc_pre  = ws;                          // (B,L,Din) [reused: carries, then ym]
  float* z_silu  = ws + SZ_BLD;
  float* xc      = ws + 2*SZ_BLD;
  float* xT      = ws + 3*SZ_BLD;
  float* dts_low = ws + 4*SZ_BLD;               // (B,K,R,L)    442,368
  float* Bln     = dts_low + (long)B_*KD*RNK*L_;      // (B,K,L,16) 1,179,648
  float* Cln     = Bln + (long)B_*KD*L_*NST;
  float* bufA    = Cln + (long)B_*KD*L_*NST;    // (B,2,Din,L)
  float* bufB    = bufA + (long)B_*2*DIN*L_;
  float* carryH  = xc_pre;                      // aliases xc_pre (dead after K2)
  float* carryP  = xc_pre + (long)6144*NCH*16;
  float* ym      = xc_pre;                      // aliases (carries dead after K4c)

  k1_inproj  <<<(B_*L_)/16,          256, 0, stream>>>(x, w_in, xc_pre, z_silu);
  k2_conv    <<<B_*6*9,              256, 0, stream>>>(xc_pre, conv_w, conv_b, xc, xT);
  k3_xdbl    <<<B_*KD*72,            256, 0, stream>>>(xc, xT, xpw, dts_low, Bln, Cln);
  k4a_carry  <<<B_*KD*12*(NCH-1)/4,  256, 0, stream>>>(xc, xT, dts_low, Bln, dtw, dtb,
                                                       A_logs, carryH, carryP);
  k4b_combine<<<(6144*16)/256,       256, 0, stream>>>(carryH, carryP);
  k4c_scan   <<<B_*KD*12*NCH/4,      256, 0, stream>>>(xc, xT, dts_low, Bln, Cln,
                                                       dtw, dtb, A_logs, carryH,
                                                       bufA, bufB);
  k5a_merge  <<<B_*9*6,              256, 0, stream>>>(bufA, bufB, xc, xT, Ds, ym);
  k5b_out    <<<B_*72*2,             256, 0, stream>>>(ym, z_silu, lnw, lnb, wout, out);
}